// Round 1
// baseline (1683.009 us; speedup 1.0000x reference)
//
#include <hip/hip_runtime.h>
#include <hip/hip_bf16.h>
#include <math.h>

#define NTOK 8192     // B*S
#define DMD  2048     // d_model
#define DCC  512      // d_cortical
#define TOKH 4194304  // NTOK*DCC

typedef __attribute__((ext_vector_type(8))) short short8;
typedef __attribute__((ext_vector_type(4))) float f32x4;

// ---------------- helpers ---------------------------------------------------
__device__ inline float bf2f(unsigned short u) {
    union { unsigned int i; float f; } x; x.i = ((unsigned int)u) << 16; return x.f;
}
__device__ inline unsigned short f2bf(float f) {
    union { float f; unsigned int i; } x; x.f = f;
    unsigned int u = x.i;
    return (unsigned short)((u + 0x7fffu + ((u >> 16) & 1u)) >> 16);
}

// async global->LDS, 16B per lane; LDS dest is wave-uniform base + lane*16.
typedef const __attribute__((address_space(1))) unsigned int* gas1_t;
typedef __attribute__((address_space(3))) unsigned int* las3_t;
__device__ inline void async16(const void* g, void* l) {
    __builtin_amdgcn_global_load_lds(
        (gas1_t)g,
        (las3_t)(unsigned int)(unsigned long long)l, 16, 0, 0);
}

// ---------------- merged fp32 -> bf16 weight conversion ---------------------
// All 7 weight tensors converted in one launch. dst segments are contiguous
// in ws in this exact order (offsets in float4 units).
struct CvtArgs { const float* src[7]; };

__global__ __launch_bounds__(256)
void wcvt_kernel(CvtArgs ca, unsigned short* __restrict__ dst)
{
    const int total = 2359296;  // f4 units
    for (int i = blockIdx.x * 256 + threadIdx.x; i < total; i += gridDim.x * 256) {
        const float* sp; int base;
        if      (i < 1048576) { sp = ca.src[0]; base = 0;       }  // proj_W
        else if (i < 1310720) { sp = ca.src[1]; base = 1048576; }  // fuse_W
        else if (i < 1572864) { sp = ca.src[2]; base = 1310720; }  // up_W
        else if (i < 1835008) { sp = ca.src[3]; base = 1572864; }  // lateral_W
        else if (i < 2031616) { sp = ca.src[4]; base = 1835008; }  // down_W
        else if (i < 2097152) { sp = ca.src[5]; base = 2031616; }  // out1_W
        else                  { sp = ca.src[6]; base = 2097152; }  // out2_W
        float4 v = ((const float4*)sp)[i - base];
        ushort4 o;
        o.x = f2bf(v.x); o.y = f2bf(v.y); o.z = f2bf(v.z); o.w = f2bf(v.w);
        ((ushort4*)dst)[i] = o;
    }
}

// ---------------- batched bf16 MFMA GEMM (m97 structure) --------------------
// C[M,N] = A[M,K] @ W[N,K]^T + bias (+add fp32) (gelu). blockIdx.z = batch slot.
// A32: A is fp32 in global, converted to bf16 during reg-staged LDS write.
struct GArgs {
    const unsigned short* A[6];
    const unsigned short* W[6];
    const float*          bias[6];
    const float*          add[6];
    void*                 C[6];
};

template<bool A32, bool OUTF32, bool GELU>
__global__ __launch_bounds__(256)
void gemm16(GArgs ga, int lda, int ldw, int ldadd, int ldc, int K)
{
    __shared__ unsigned short As[128 * 32];   // 8 KB
    __shared__ unsigned short Bs[128 * 32];   // 8 KB

    const int z    = blockIdx.z;
    const int tid  = threadIdx.x;
    const int wave = tid >> 6;
    const int lane = tid & 63;
    const int bm   = blockIdx.y * 128;
    const int bn   = blockIdx.x * 128;
    const int wr   = wave >> 1;   // 0..1 -> 64-row half
    const int wc   = wave & 1;    // 0..1 -> 64-col half

    const unsigned short* Ap = ga.A[z];
    const unsigned short* Wp = ga.W[z];

    const int lrow = lane >> 2;         // 0..15
    const int lcol = (lane & 3) * 8;    // 0,8,16,24

    f32x4 acc[4][4] = {};

    for (int k0 = 0; k0 < K; k0 += 32) {
        if constexpr (A32) {
            // reg-staged: load fp32, convert, ds_write (128x32 tile)
            const float* Af = (const float*)Ap;
            #pragma unroll
            for (int r = 0; r < 4; ++r) {
                int idx = r * 256 + tid;
                int row = idx >> 3, c4 = (idx & 7) * 4;
                float4 v = *(const float4*)(Af + (size_t)(bm + row) * lda + k0 + c4);
                ushort4 o;
                o.x = f2bf(v.x); o.y = f2bf(v.y); o.z = f2bf(v.z); o.w = f2bf(v.w);
                *(ushort4*)&As[row * 32 + c4] = o;
            }
        } else {
            #pragma unroll
            for (int r = 0; r < 2; ++r) {
                int c = wave + r * 4;
                async16(Ap + (size_t)(bm + c * 16 + lrow) * lda + k0 + lcol, As + c * 512);
            }
        }
        #pragma unroll
        for (int r = 0; r < 2; ++r) {
            int c = wave + r * 4;
            async16(Wp + (size_t)(bn + c * 16 + lrow) * ldw + k0 + lcol, Bs + c * 512);
        }
        __syncthreads();

        short8 af[4], bfr[4];
        #pragma unroll
        for (int i = 0; i < 4; ++i) {
            af[i]  = *(const short8*)&As[(wr * 64 + i * 16 + (lane & 15)) * 32 + (lane >> 4) * 8];
            bfr[i] = *(const short8*)&Bs[(wc * 64 + i * 16 + (lane & 15)) * 32 + (lane >> 4) * 8];
        }
        #pragma unroll
        for (int mi = 0; mi < 4; ++mi)
            #pragma unroll
            for (int ni = 0; ni < 4; ++ni)
                acc[mi][ni] = __builtin_amdgcn_mfma_f32_16x16x32_bf16(
                    af[mi], bfr[ni], acc[mi][ni], 0, 0, 0);
        __syncthreads();
    }

    // epilogue: C/D layout col=lane&15, row=(lane>>4)*4+reg
    const float* bias = ga.bias[z];
    const float* add  = ga.add[z];
    #pragma unroll
    for (int ni = 0; ni < 4; ++ni) {
        int col = bn + wc * 64 + ni * 16 + (lane & 15);
        float bv = bias ? bias[col] : 0.0f;
        #pragma unroll
        for (int mi = 0; mi < 4; ++mi) {
            #pragma unroll
            for (int r = 0; r < 4; ++r) {
                int row = bm + wr * 64 + mi * 16 + (lane >> 4) * 4 + r;
                float vv = acc[mi][ni][r] + bv;
                if (GELU) vv = 0.5f * vv * (1.0f + erff(vv * 0.7071067811865475f));
                if (OUTF32) {
                    if (add) vv += add[(size_t)row * ldadd + col];
                    ((float*)ga.C[z])[(size_t)row * ldc + col] = vv;
                } else {
                    ((unsigned short*)ga.C[z])[(size_t)row * ldc + col] = f2bf(vv);
                }
            }
        }
    }
}

// ---------------- fused GEMM + LN (+update) ---------------------------------
// Block tile: 32 rows x 512 cols, K=512, 4 waves (wave w owns cols w*128..+127).
// MODE 0: out = LN(A@W^T + bias)                       (bottom-up pass)
// MODE 1: comp = LN1(A@W^T + bias);
//         val  = a + 0.5*(comp - t)*sigmoid(logit) + 0.1*lat;
//         out  = LN2(val)                              (settle update, in-place)
// LDS: As 2x2KB dbuf, Bs 2x32KB dbuf (Bs[0] reused as comp staging), red 1KB.
__device__ inline int csw(int rl, int col) {
    // XOR-swizzle comp staging: spread the 4 (lane>>4) groups across banks
    return rl * 512 + (col ^ (((rl >> 2) & 3) << 4));
}

template<int MODE>
__global__ __launch_bounds__(256)
void gemm_fused(const unsigned short* __restrict__ Ap,
                const unsigned short* __restrict__ Wp,
                const float* __restrict__ bias,
                const float* __restrict__ g,
                const float* __restrict__ b,
                const unsigned short* a_in,
                const unsigned short* t_in,
                const unsigned short* __restrict__ lat_in,
                const float* __restrict__ logit,
                unsigned short* outp)
{
    __shared__ unsigned short As[2][32 * 32];    //  4 KB
    __shared__ unsigned short Bs[2][512 * 32];   // 64 KB
    __shared__ float red[2][4][32];              //  1 KB

    const int tid  = threadIdx.x;
    const int wave = tid >> 6;
    const int lane = tid & 63;
    const int lrow = lane >> 2;        // 0..15
    const int lc8  = (lane & 3) * 8;   // 0,8,16,24
    const int bm   = blockIdx.x * 32;
    const int l15  = lane & 15;
    const int lh   = lane >> 4;

    f32x4 acc[2][8] = {};

    // prologue stage buf0, k=0
    if (wave < 2)
        async16(Ap + (size_t)(bm + wave * 16 + lrow) * DCC + lc8, &As[0][wave * 512]);
    #pragma unroll
    for (int r = 0; r < 8; ++r)
        async16(Wp + (size_t)((r * 4 + wave) * 16 + lrow) * DCC + lc8,
                &Bs[0][(r * 4 + wave) * 512]);
    __syncthreads();   // drains vmcnt(0) -> buf0 ready

    for (int t = 0; t < 16; ++t) {
        const int cur = t & 1;
        if (t < 15) {  // prefetch next K-tile into other buffer (2-phase)
            const int k0 = (t + 1) * 32;
            if (wave < 2)
                async16(Ap + (size_t)(bm + wave * 16 + lrow) * DCC + k0 + lc8,
                        &As[cur ^ 1][wave * 512]);
            #pragma unroll
            for (int r = 0; r < 8; ++r)
                async16(Wp + (size_t)((r * 4 + wave) * 16 + lrow) * DCC + k0 + lc8,
                        &Bs[cur ^ 1][(r * 4 + wave) * 512]);
        }
        short8 af[2], bfr[8];
        #pragma unroll
        for (int mi = 0; mi < 2; ++mi)
            af[mi] = *(const short8*)&As[cur][(mi * 16 + l15) * 32 + lh * 8];
        #pragma unroll
        for (int ni = 0; ni < 8; ++ni)
            bfr[ni] = *(const short8*)&Bs[cur][(wave * 128 + ni * 16 + l15) * 32 + lh * 8];
        #pragma unroll
        for (int mi = 0; mi < 2; ++mi)
            #pragma unroll
            for (int ni = 0; ni < 8; ++ni)
                acc[mi][ni] = __builtin_amdgcn_mfma_f32_16x16x32_bf16(
                    af[mi], bfr[ni], acc[mi][ni], 0, 0, 0);
        __syncthreads();   // drains next-tile vmcnt + this-tile lgkm
    }

    // ---- phase 1: bias + LN1 row stats in MFMA layout ----
    float bv[8], gv[8], bbv[8];
    #pragma unroll
    for (int ni = 0; ni < 8; ++ni) {
        int col = wave * 128 + ni * 16 + l15;
        bv[ni] = bias[col]; gv[ni] = g[col]; bbv[ni] = b[col];
    }

    float ps[2][4], pq[2][4];
    #pragma unroll
    for (int mi = 0; mi < 2; ++mi)
        #pragma unroll
        for (int rr = 0; rr < 4; ++rr) {
            float s = 0.f, q = 0.f;
            #pragma unroll
            for (int ni = 0; ni < 8; ++ni) {
                float v = acc[mi][ni][rr] + bv[ni];
                acc[mi][ni][rr] = v;
                s += v; q += v * v;
            }
            #pragma unroll
            for (int off = 1; off < 16; off <<= 1) {
                s += __shfl_xor(s, off, 64);
                q += __shfl_xor(q, off, 64);
            }
            ps[mi][rr] = s; pq[mi][rr] = q;
        }
    if (l15 == 0) {
        #pragma unroll
        for (int mi = 0; mi < 2; ++mi)
            #pragma unroll
            for (int rr = 0; rr < 4; ++rr) {
                int rl = mi * 16 + lh * 4 + rr;
                red[0][wave][rl] = ps[mi][rr];
                red[1][wave][rl] = pq[mi][rr];
            }
    }
    __syncthreads();

    // comp = LN1 result, staged to LDS (reuse Bs[0]: 32*512 bf16 = 32 KB)
    unsigned short* compS = &Bs[0][0];
    #pragma unroll
    for (int mi = 0; mi < 2; ++mi)
        #pragma unroll
        for (int rr = 0; rr < 4; ++rr) {
            int rl = mi * 16 + lh * 4 + rr;
            float s = red[0][0][rl] + red[0][1][rl] + red[0][2][rl] + red[0][3][rl];
            float q = red[1][0][rl] + red[1][1][rl] + red[1][2][rl] + red[1][3][rl];
            float m1 = s * (1.0f / DCC);
            float r1 = rsqrtf(q * (1.0f / DCC) - m1 * m1 + 1e-5f);
            #pragma unroll
            for (int ni = 0; ni < 8; ++ni) {
                int col = wave * 128 + ni * 16 + l15;
                compS[csw(rl, col)] = f2bf((acc[mi][ni][rr] - m1) * r1 * gv[ni] + bbv[ni]);
            }
        }
    __syncthreads();

    // ---- phase 2: row-mapped (wave owns 8 rows, lane owns 8 contiguous cols)
    float gr[8], br[8], pr[8];
    if constexpr (MODE == 1) {
        const int c0 = lane * 8;
        float4 g0 = *(const float4*)(g + c0),     g1 = *(const float4*)(g + c0 + 4);
        float4 b0 = *(const float4*)(b + c0),     b1 = *(const float4*)(b + c0 + 4);
        float4 p0 = *(const float4*)(logit + c0), p1 = *(const float4*)(logit + c0 + 4);
        float gt[8] = {g0.x,g0.y,g0.z,g0.w,g1.x,g1.y,g1.z,g1.w};
        float bt[8] = {b0.x,b0.y,b0.z,b0.w,b1.x,b1.y,b1.z,b1.w};
        float pt[8] = {p0.x,p0.y,p0.z,p0.w,p1.x,p1.y,p1.z,p1.w};
        #pragma unroll
        for (int j = 0; j < 8; ++j) {
            gr[j] = gt[j]; br[j] = bt[j];
            pr[j] = 1.0f / (1.0f + __expf(-pt[j]));
        }
    }

    #pragma unroll
    for (int rr = 0; rr < 8; ++rr) {
        const int rl = wave * 8 + rr;
        const size_t gbase = (size_t)(bm + rl) * DCC + lane * 8;
        short8 cm = *(const short8*)&compS[csw(rl, lane * 8)];
        if constexpr (MODE == 0) {
            *(short8*)(outp + gbase) = cm;
        } else {
            short8 ar = *(const short8*)(a_in + gbase);
            short8 tr = *(const short8*)(t_in + gbase);
            short8 lr = *(const short8*)(lat_in + gbase);
            float tv[8], s = 0.f, q = 0.f;
            #pragma unroll
            for (int j = 0; j < 8; ++j) {
                float val = bf2f((unsigned short)ar[j])
                          + 0.5f * (bf2f((unsigned short)cm[j]) - bf2f((unsigned short)tr[j])) * pr[j]
                          + 0.1f * bf2f((unsigned short)lr[j]);
                tv[j] = val; s += val; q += val * val;
            }
            #pragma unroll
            for (int off = 1; off < 64; off <<= 1) {
                s += __shfl_xor(s, off, 64);
                q += __shfl_xor(q, off, 64);
            }
            float m2 = s * (1.0f / DCC);
            float r2 = rsqrtf(q * (1.0f / DCC) - m2 * m2 + 1e-5f);
            short8 o;
            #pragma unroll
            for (int j = 0; j < 8; ++j)
                o[j] = (short)f2bf((tv[j] - m2) * r2 * gr[j] + br[j]);
            *(short8*)(outp + gbase) = o;
        }
    }
}

// ---------------------------------------------------------------------------
extern "C" void kernel_launch(void* const* d_in, const int* in_sizes, int n_in,
                              void* d_out, int out_size, void* d_ws, size_t ws_size,
                              hipStream_t stream)
{
    const float* qwen   = (const float*)d_in[0];
    const float* obs    = (const float*)d_in[1];
    const float* proj_W = (const float*)d_in[2];
    const float* proj_b = (const float*)d_in[3];
    const float* fuse_W = (const float*)d_in[4];
    const float* fuse_b = (const float*)d_in[5];
    const float* up_W   = (const float*)d_in[6];
    const float* up_b   = (const float*)d_in[7];
    const float* lat_W  = (const float*)d_in[8];
    const float* lat_b  = (const float*)d_in[9];
    const float* plogit = (const float*)d_in[10];
    const float* ln_g   = (const float*)d_in[11];
    const float* ln_b   = (const float*)d_in[12];
    const float* down_W = (const float*)d_in[13];
    const float* down_b = (const float*)d_in[14];
    const float* out1_W = (const float*)d_in[15];
    const float* out1_b = (const float*)d_in[16];
    const float* out2_W = (const float*)d_in[17];
    const float* out2_b = (const float*)d_in[18];
    float* out = (float*)d_out;

    // ---- ws layout (ushort): cat | x0 | acts0..3 | weights
    unsigned short* wsu = (unsigned short*)d_ws;
    unsigned short* catbuf = wsu;                          // 16,777,216
    unsigned short* x0b    = wsu + 16777216;               // 4,194,304
    unsigned short* acts16[4] = {
        wsu + 20971520, wsu + 20971520 + TOKH,
        wsu + 20971520 + 2 * TOKH, wsu + 20971520 + 3 * TOKH };
    unsigned short* w16    = wsu + 37748736;               // 9,437,184
    unsigned short* projW16 = w16;                         // 4,194,304
    unsigned short* fuseW16 = w16 + 4194304;               // 1,048,576
    unsigned short* upW16   = w16 + 5242880;               // 1,048,576
    // latW16 = w16 + 6291456, downW16 = w16 + 7340032 (used via batched GArgs)
    unsigned short* latW16  = w16 + 6291456;
    unsigned short* downW16 = w16 + 7340032;
    unsigned short* out1W16 = w16 + 8126464;               //   262,144
    unsigned short* out2W16 = w16 + 8388608;               // 1,048,576
    unsigned short* h16     = catbuf;                      // alias (cat dead after fuse)

    // ---- d_out overlays (64 MiB, fully rewritten by final GEMM):
    // pred a/b + lat0..3 = 6 x 8.4 MB
    unsigned short* outu = (unsigned short*)d_out;
    unsigned short* pred16a = outu;
    unsigned short* pred16b = outu + TOKH;
    unsigned short* lat16[4] = { outu + 2*TOKH, outu + 3*TOKH, outu + 4*TOKH, outu + 5*TOKH };

    dim3 blk(256);

    // ---- all weight conversions in one launch
    {
        CvtArgs ca;
        ca.src[0] = proj_W; ca.src[1] = fuse_W; ca.src[2] = up_W;
        ca.src[3] = lat_W;  ca.src[4] = down_W; ca.src[5] = out1_W;
        ca.src[6] = out2_W;
        wcvt_kernel<<<dim3(2048), blk, 0, stream>>>(ca, w16);
    }

    // ---- proj: single z=4 launch directly off fp32 obs (A32 staging)
    {
        GArgs a{};
        for (int o = 0; o < 4; ++o) {
            a.A[o]    = (const unsigned short*)(obs + (size_t)o * NTOK * DMD);
            a.W[o]    = projW16 + (size_t)o * DCC * DMD;
            a.bias[o] = proj_b + o * DCC;
            a.C[o]    = catbuf + o * DCC;        // ldc = 2048, column offset
        }
        gemm16<true, false, false><<<dim3(DCC/128, NTOK/128, 4), blk, 0, stream>>>(
            a, DMD, DMD, 0, 4 * DCC, DMD);
    }
    // ---- fuse: x0 = cat @ fuse_W^T + fuse_b  (K=2048)
    {
        GArgs a{};
        a.A[0] = catbuf; a.W[0] = fuseW16; a.bias[0] = fuse_b; a.C[0] = x0b;
        gemm16<false, false, false><<<dim3(DCC/128, NTOK/128, 1), blk, 0, stream>>>(
            a, 4 * DCC, 4 * DCC, 0, DCC, 4 * DCC);
    }

    // ---- initial bottom-up pass: fused GEMM+LN
    for (int i = 0; i < 4; ++i) {
        gemm_fused<0><<<dim3(NTOK/32), blk, 0, stream>>>(
            (i == 0) ? x0b : acts16[i - 1],
            upW16 + (size_t)i * DCC * DCC, up_b + i * DCC,
            ln_g + i * DCC, ln_b + i * DCC,
            nullptr, nullptr, nullptr, nullptr, acts16[i]);
    }

    // ---- settling iterations
    for (int s = 0; s < 5; ++s) {
        // batched independents: pred0, pred1, lat0..lat3 (all from pre-sweep acts)
        {
            GArgs a{};
            a.A[0] = acts16[1]; a.W[0] = downW16 + (size_t)1 * DCC * DCC;
            a.bias[0] = down_b + 1 * DCC; a.C[0] = pred16a;
            a.A[1] = acts16[2]; a.W[1] = downW16 + (size_t)2 * DCC * DCC;
            a.bias[1] = down_b + 2 * DCC; a.C[1] = pred16b;
            for (int i = 0; i < 4; ++i) {
                a.A[2 + i] = acts16[i];
                a.W[2 + i] = latW16 + (size_t)i * DCC * DCC;
                a.bias[2 + i] = lat_b + i * DCC;
                a.C[2 + i] = lat16[i];
            }
            gemm16<false, false, false><<<dim3(DCC/128, NTOK/128, 6), blk, 0, stream>>>(
                a, DCC, DCC, 0, DCC, DCC);
        }
        // sequential chain: fused up-GEMM + update per layer (in-place on acts)
        for (int i = 0; i < 4; ++i) {
            const unsigned short* tgt =
                (i == 0) ? pred16a : (i == 1) ? pred16b : acts16[i];
            gemm_fused<1><<<dim3(NTOK/32), blk, 0, stream>>>(
                (i == 0) ? x0b : acts16[i - 1],
                upW16 + (size_t)i * DCC * DCC, up_b + i * DCC,
                ln_g + i * DCC, ln_b + i * DCC,
                acts16[i], tgt, lat16[i], plogit + i * DCC, acts16[i]);
        }
    }

    // ---- head
    {
        GArgs a{};
        a.A[0] = acts16[3]; a.W[0] = out1W16; a.bias[0] = out1_b; a.C[0] = h16;
        gemm16<false, false, true><<<dim3(DCC/128, NTOK/128, 1), blk, 0, stream>>>(
            a, DCC, DCC, 0, DCC, DCC);
    }
    {
        GArgs a{};
        a.A[0] = h16; a.W[0] = out2W16; a.bias[0] = out2_b;
        a.add[0] = qwen; a.C[0] = out;
        gemm16<false, true, false><<<dim3(DMD/128, NTOK/128, 1), blk, 0, stream>>>(
            a, DCC, DCC, DMD, DMD, DCC);
    }
}

// Round 2
// 1595.140 us; speedup vs baseline: 1.0551x; 1.0551x over previous
//
#include <hip/hip_runtime.h>
#include <hip/hip_bf16.h>
#include <math.h>

#define NTOK 8192     // B*S
#define DMD  2048     // d_model
#define DCC  512      // d_cortical
#define TOKH 4194304  // NTOK*DCC

typedef __attribute__((ext_vector_type(8))) short short8;
typedef __attribute__((ext_vector_type(4))) float f32x4;

// ---------------- helpers ---------------------------------------------------
__device__ inline float bf2f(unsigned short u) {
    union { unsigned int i; float f; } x; x.i = ((unsigned int)u) << 16; return x.f;
}
__device__ inline unsigned short f2bf(float f) {
    union { float f; unsigned int i; } x; x.f = f;
    unsigned int u = x.i;
    return (unsigned short)((u + 0x7fffu + ((u >> 16) & 1u)) >> 16);
}

// async global->LDS, 16B per lane; LDS dest is wave-uniform base + lane*16.
typedef const __attribute__((address_space(1))) unsigned int* gas1_t;
typedef __attribute__((address_space(3))) unsigned int* las3_t;
__device__ inline void async16(const void* g, void* l) {
    __builtin_amdgcn_global_load_lds(
        (gas1_t)g,
        (las3_t)(unsigned int)(unsigned long long)l, 16, 0, 0);
}

// ---------------- fp32 -> bf16 conversion (bulk activations) ----------------
__global__ __launch_bounds__(256)
void cvt_kernel(const float* __restrict__ s, unsigned short* __restrict__ d, int n4)
{
    int i = blockIdx.x * 256 + threadIdx.x;
    if (i >= n4) return;
    float4 v = ((const float4*)s)[i];
    ushort4 o;
    o.x = f2bf(v.x); o.y = f2bf(v.y); o.z = f2bf(v.z); o.w = f2bf(v.w);
    ((ushort4*)d)[i] = o;
}

// ---------------- merged fp32 -> bf16 weight conversion ---------------------
struct CvtArgs { const float* src[7]; };

__global__ __launch_bounds__(256)
void wcvt_kernel(CvtArgs ca, unsigned short* __restrict__ dst)
{
    const int total = 2359296;  // f4 units
    for (int i = blockIdx.x * 256 + threadIdx.x; i < total; i += gridDim.x * 256) {
        const float* sp; int base;
        if      (i < 1048576) { sp = ca.src[0]; base = 0;       }  // proj_W
        else if (i < 1310720) { sp = ca.src[1]; base = 1048576; }  // fuse_W
        else if (i < 1572864) { sp = ca.src[2]; base = 1310720; }  // up_W
        else if (i < 1835008) { sp = ca.src[3]; base = 1572864; }  // lateral_W
        else if (i < 2031616) { sp = ca.src[4]; base = 1835008; }  // down_W
        else if (i < 2097152) { sp = ca.src[5]; base = 2031616; }  // out1_W
        else                  { sp = ca.src[6]; base = 2097152; }  // out2_W
        float4 v = ((const float4*)sp)[i - base];
        ushort4 o;
        o.x = f2bf(v.x); o.y = f2bf(v.y); o.z = f2bf(v.z); o.w = f2bf(v.w);
        ((ushort4*)dst)[i] = o;
    }
}

// ---------------- batched bf16 MFMA GEMM (m97 structure + XCD swizzle) ------
// C[M,N] = A[M,K] @ W[N,K]^T + bias (+add fp32) (gelu). blockIdx.z = batch slot.
// Chunked XCD swizzle: consecutive swz ids (same A panel, different bn) land on
// the same XCD so the A panel re-read is an L2 hit. Requires nwg % 8 == 0
// (all launches here: 256 or 1024 blocks per z).
struct GArgs {
    const unsigned short* A[6];
    const unsigned short* W[6];
    const float*          bias[6];
    const float*          add[6];
    void*                 C[6];
};

template<bool OUTF32, bool GELU>
__global__ __launch_bounds__(256)
void gemm16(GArgs ga, int lda, int ldw, int ldadd, int ldc, int K)
{
    __shared__ unsigned short As[128 * 32];   // 8 KB
    __shared__ unsigned short Bs[128 * 32];   // 8 KB

    const int z    = blockIdx.z;
    const int tid  = threadIdx.x;
    const int wave = tid >> 6;
    const int lane = tid & 63;

    // XCD-chunked bijective swizzle (nwg % 8 == 0)
    const int nwg   = gridDim.x * gridDim.y;
    const int bid   = blockIdx.y * gridDim.x + blockIdx.x;
    const int swz   = (bid & 7) * (nwg >> 3) + (bid >> 3);
    const int bn    = (swz % gridDim.x) * 128;
    const int bm    = (swz / gridDim.x) * 128;

    const int wr   = wave >> 1;   // 0..1 -> 64-row half
    const int wc   = wave & 1;    // 0..1 -> 64-col half

    const unsigned short* Ap = ga.A[z];
    const unsigned short* Wp = ga.W[z];

    const int lrow = lane >> 2;         // 0..15
    const int lcol = (lane & 3) * 8;    // 0,8,16,24

    f32x4 acc[4][4] = {};

    for (int k0 = 0; k0 < K; k0 += 32) {
        #pragma unroll
        for (int r = 0; r < 2; ++r) {
            int c = wave + r * 4;
            async16(Ap + (size_t)(bm + c * 16 + lrow) * lda + k0 + lcol, As + c * 512);
            async16(Wp + (size_t)(bn + c * 16 + lrow) * ldw + k0 + lcol, Bs + c * 512);
        }
        __syncthreads();

        short8 af[4], bfr[4];
        #pragma unroll
        for (int i = 0; i < 4; ++i) {
            af[i]  = *(const short8*)&As[(wr * 64 + i * 16 + (lane & 15)) * 32 + (lane >> 4) * 8];
            bfr[i] = *(const short8*)&Bs[(wc * 64 + i * 16 + (lane & 15)) * 32 + (lane >> 4) * 8];
        }
        #pragma unroll
        for (int mi = 0; mi < 4; ++mi)
            #pragma unroll
            for (int ni = 0; ni < 4; ++ni)
                acc[mi][ni] = __builtin_amdgcn_mfma_f32_16x16x32_bf16(
                    af[mi], bfr[ni], acc[mi][ni], 0, 0, 0);
        __syncthreads();
    }

    // epilogue: C/D layout col=lane&15, row=(lane>>4)*4+reg
    const float* bias = ga.bias[z];
    const float* add  = ga.add[z];
    #pragma unroll
    for (int ni = 0; ni < 4; ++ni) {
        int col = bn + wc * 64 + ni * 16 + (lane & 15);
        float bv = bias ? bias[col] : 0.0f;
        #pragma unroll
        for (int mi = 0; mi < 4; ++mi) {
            #pragma unroll
            for (int r = 0; r < 4; ++r) {
                int row = bm + wr * 64 + mi * 16 + (lane >> 4) * 4 + r;
                float vv = acc[mi][ni][r] + bv;
                if (GELU) vv = 0.5f * vv * (1.0f + erff(vv * 0.7071067811865475f));
                if (OUTF32) {
                    if (add) vv += add[(size_t)row * ldadd + col];
                    ((float*)ga.C[z])[(size_t)row * ldc + col] = vv;
                } else {
                    ((unsigned short*)ga.C[z])[(size_t)row * ldc + col] = f2bf(vv);
                }
            }
        }
    }
}

// ---------------- fused GEMM + LN (+update) ---------------------------------
// Block tile: 32 rows x 512 cols, K=512, 4 waves (wave w owns cols w*128..+127).
// MODE 0: out = LN(A@W^T + bias)                       (bottom-up pass)
// MODE 1: comp = LN1(A@W^T + bias);
//         val  = a + 0.5*(comp - t)*sigmoid(logit) + 0.1*lat;
//         out  = LN2(val)                              (settle update, in-place)
__device__ inline int csw(int rl, int col) {
    return rl * 512 + (col ^ (((rl >> 2) & 3) << 4));
}

template<int MODE>
__global__ __launch_bounds__(256)
void gemm_fused(const unsigned short* __restrict__ Ap,
                const unsigned short* __restrict__ Wp,
                const float* __restrict__ bias,
                const float* __restrict__ g,
                const float* __restrict__ b,
                const unsigned short* a_in,
                const unsigned short* t_in,
                const unsigned short* __restrict__ lat_in,
                const float* __restrict__ logit,
                unsigned short* outp)
{
    __shared__ unsigned short As[2][32 * 32];    //  4 KB
    __shared__ unsigned short Bs[2][512 * 32];   // 64 KB
    __shared__ float red[2][4][32];              //  1 KB

    const int tid  = threadIdx.x;
    const int wave = tid >> 6;
    const int lane = tid & 63;
    const int lrow = lane >> 2;        // 0..15
    const int lc8  = (lane & 3) * 8;   // 0,8,16,24
    const int bm   = blockIdx.x * 32;
    const int l15  = lane & 15;
    const int lh   = lane >> 4;

    f32x4 acc[2][8] = {};

    // prologue stage buf0, k=0
    if (wave < 2)
        async16(Ap + (size_t)(bm + wave * 16 + lrow) * DCC + lc8, &As[0][wave * 512]);
    #pragma unroll
    for (int r = 0; r < 8; ++r)
        async16(Wp + (size_t)((r * 4 + wave) * 16 + lrow) * DCC + lc8,
                &Bs[0][(r * 4 + wave) * 512]);
    __syncthreads();   // drains vmcnt(0) -> buf0 ready

    for (int t = 0; t < 16; ++t) {
        const int cur = t & 1;
        if (t < 15) {  // prefetch next K-tile into other buffer (2-phase)
            const int k0 = (t + 1) * 32;
            if (wave < 2)
                async16(Ap + (size_t)(bm + wave * 16 + lrow) * DCC + k0 + lc8,
                        &As[cur ^ 1][wave * 512]);
            #pragma unroll
            for (int r = 0; r < 8; ++r)
                async16(Wp + (size_t)((r * 4 + wave) * 16 + lrow) * DCC + k0 + lc8,
                        &Bs[cur ^ 1][(r * 4 + wave) * 512]);
        }
        short8 af[2], bfr[8];
        #pragma unroll
        for (int mi = 0; mi < 2; ++mi)
            af[mi] = *(const short8*)&As[cur][(mi * 16 + l15) * 32 + lh * 8];
        #pragma unroll
        for (int ni = 0; ni < 8; ++ni)
            bfr[ni] = *(const short8*)&Bs[cur][(wave * 128 + ni * 16 + l15) * 32 + lh * 8];
        #pragma unroll
        for (int mi = 0; mi < 2; ++mi)
            #pragma unroll
            for (int ni = 0; ni < 8; ++ni)
                acc[mi][ni] = __builtin_amdgcn_mfma_f32_16x16x32_bf16(
                    af[mi], bfr[ni], acc[mi][ni], 0, 0, 0);
        __syncthreads();   // drains next-tile vmcnt + this-tile lgkm
    }

    // ---- phase 1: bias + LN1 row stats in MFMA layout ----
    float bv[8], gv[8], bbv[8];
    #pragma unroll
    for (int ni = 0; ni < 8; ++ni) {
        int col = wave * 128 + ni * 16 + l15;
        bv[ni] = bias[col]; gv[ni] = g[col]; bbv[ni] = b[col];
    }

    float ps[2][4], pq[2][4];
    #pragma unroll
    for (int mi = 0; mi < 2; ++mi)
        #pragma unroll
        for (int rr = 0; rr < 4; ++rr) {
            float s = 0.f, q = 0.f;
            #pragma unroll
            for (int ni = 0; ni < 8; ++ni) {
                float v = acc[mi][ni][rr] + bv[ni];
                acc[mi][ni][rr] = v;
                s += v; q += v * v;
            }
            #pragma unroll
            for (int off = 1; off < 16; off <<= 1) {
                s += __shfl_xor(s, off, 64);
                q += __shfl_xor(q, off, 64);
            }
            ps[mi][rr] = s; pq[mi][rr] = q;
        }
    if (l15 == 0) {
        #pragma unroll
        for (int mi = 0; mi < 2; ++mi)
            #pragma unroll
            for (int rr = 0; rr < 4; ++rr) {
                int rl = mi * 16 + lh * 4 + rr;
                red[0][wave][rl] = ps[mi][rr];
                red[1][wave][rl] = pq[mi][rr];
            }
    }
    __syncthreads();

    // comp = LN1 result, staged to LDS (reuse Bs[0]: 32*512 bf16 = 32 KB)
    unsigned short* compS = &Bs[0][0];
    #pragma unroll
    for (int mi = 0; mi < 2; ++mi)
        #pragma unroll
        for (int rr = 0; rr < 4; ++rr) {
            int rl = mi * 16 + lh * 4 + rr;
            float s = red[0][0][rl] + red[0][1][rl] + red[0][2][rl] + red[0][3][rl];
            float q = red[1][0][rl] + red[1][1][rl] + red[1][2][rl] + red[1][3][rl];
            float m1 = s * (1.0f / DCC);
            float r1 = rsqrtf(q * (1.0f / DCC) - m1 * m1 + 1e-5f);
            #pragma unroll
            for (int ni = 0; ni < 8; ++ni) {
                int col = wave * 128 + ni * 16 + l15;
                compS[csw(rl, col)] = f2bf((acc[mi][ni][rr] - m1) * r1 * gv[ni] + bbv[ni]);
            }
        }
    __syncthreads();

    // ---- phase 2: row-mapped (wave owns 8 rows, lane owns 8 contiguous cols)
    float gr[8], br[8], pr[8];
    if constexpr (MODE == 1) {
        const int c0 = lane * 8;
        float4 g0 = *(const float4*)(g + c0),     g1 = *(const float4*)(g + c0 + 4);
        float4 b0 = *(const float4*)(b + c0),     b1 = *(const float4*)(b + c0 + 4);
        float4 p0 = *(const float4*)(logit + c0), p1 = *(const float4*)(logit + c0 + 4);
        float gt[8] = {g0.x,g0.y,g0.z,g0.w,g1.x,g1.y,g1.z,g1.w};
        float bt[8] = {b0.x,b0.y,b0.z,b0.w,b1.x,b1.y,b1.z,b1.w};
        float pt[8] = {p0.x,p0.y,p0.z,p0.w,p1.x,p1.y,p1.z,p1.w};
        #pragma unroll
        for (int j = 0; j < 8; ++j) {
            gr[j] = gt[j]; br[j] = bt[j];
            pr[j] = 1.0f / (1.0f + __expf(-pt[j]));
        }
    }

    #pragma unroll
    for (int rr = 0; rr < 8; ++rr) {
        const int rl = wave * 8 + rr;
        const size_t gbase = (size_t)(bm + rl) * DCC + lane * 8;
        short8 cm = *(const short8*)&compS[csw(rl, lane * 8)];
        if constexpr (MODE == 0) {
            *(short8*)(outp + gbase) = cm;
        } else {
            short8 ar = *(const short8*)(a_in + gbase);
            short8 tr = *(const short8*)(t_in + gbase);
            short8 lr = *(const short8*)(lat_in + gbase);
            float tv[8], s = 0.f, q = 0.f;
            #pragma unroll
            for (int j = 0; j < 8; ++j) {
                float val = bf2f((unsigned short)ar[j])
                          + 0.5f * (bf2f((unsigned short)cm[j]) - bf2f((unsigned short)tr[j])) * pr[j]
                          + 0.1f * bf2f((unsigned short)lr[j]);
                tv[j] = val; s += val; q += val * val;
            }
            #pragma unroll
            for (int off = 1; off < 64; off <<= 1) {
                s += __shfl_xor(s, off, 64);
                q += __shfl_xor(q, off, 64);
            }
            float m2 = s * (1.0f / DCC);
            float r2 = rsqrtf(q * (1.0f / DCC) - m2 * m2 + 1e-5f);
            short8 o;
            #pragma unroll
            for (int j = 0; j < 8; ++j)
                o[j] = (short)f2bf((tv[j] - m2) * r2 * gr[j] + br[j]);
            *(short8*)(outp + gbase) = o;
        }
    }
}

// ---------------------------------------------------------------------------
extern "C" void kernel_launch(void* const* d_in, const int* in_sizes, int n_in,
                              void* d_out, int out_size, void* d_ws, size_t ws_size,
                              hipStream_t stream)
{
    const float* qwen   = (const float*)d_in[0];
    const float* obs    = (const float*)d_in[1];
    const float* proj_W = (const float*)d_in[2];
    const float* proj_b = (const float*)d_in[3];
    const float* fuse_W = (const float*)d_in[4];
    const float* fuse_b = (const float*)d_in[5];
    const float* up_W   = (const float*)d_in[6];
    const float* up_b   = (const float*)d_in[7];
    const float* lat_W  = (const float*)d_in[8];
    const float* lat_b  = (const float*)d_in[9];
    const float* plogit = (const float*)d_in[10];
    const float* ln_g   = (const float*)d_in[11];
    const float* ln_b   = (const float*)d_in[12];
    const float* down_W = (const float*)d_in[13];
    const float* down_b = (const float*)d_in[14];
    const float* out1_W = (const float*)d_in[15];
    const float* out1_b = (const float*)d_in[16];
    const float* out2_W = (const float*)d_in[17];
    const float* out2_b = (const float*)d_in[18];
    float* out = (float*)d_out;

    // ---- ws layout (ushort): cat | x0 | acts0..3 | weights
    unsigned short* wsu = (unsigned short*)d_ws;
    unsigned short* catbuf = wsu;                          // 16,777,216
    unsigned short* x0b    = wsu + 16777216;               // 4,194,304
    unsigned short* acts16[4] = {
        wsu + 20971520, wsu + 20971520 + TOKH,
        wsu + 20971520 + 2 * TOKH, wsu + 20971520 + 3 * TOKH };
    unsigned short* w16    = wsu + 37748736;               // 9,437,184
    unsigned short* projW16 = w16;                         // 4,194,304
    unsigned short* fuseW16 = w16 + 4194304;               // 1,048,576
    unsigned short* upW16   = w16 + 5242880;               // 1,048,576
    unsigned short* latW16  = w16 + 6291456;               // 1,048,576
    unsigned short* downW16 = w16 + 7340032;               //   786,432
    unsigned short* out1W16 = w16 + 8126464;               //   262,144
    unsigned short* out2W16 = w16 + 8388608;               // 1,048,576
    unsigned short* h16     = catbuf;                      // alias (cat dead after fuse)

    // ---- d_out overlays (64 MiB):
    // phase A: two bf16 obs slices (2 x 32 MiB = exactly d_out)
    // phase B: pred a/b + lat0..3 (6 x 8.4 MB)
    unsigned short* outu = (unsigned short*)d_out;
    unsigned short* pred16a = outu;
    unsigned short* pred16b = outu + TOKH;
    unsigned short* lat16[4] = { outu + 2*TOKH, outu + 3*TOKH, outu + 4*TOKH, outu + 5*TOKH };

    dim3 blk(256);

    // ---- all weight conversions in one launch
    {
        CvtArgs ca;
        ca.src[0] = proj_W; ca.src[1] = fuse_W; ca.src[2] = up_W;
        ca.src[3] = lat_W;  ca.src[4] = down_W; ca.src[5] = out1_W;
        ca.src[6] = out2_W;
        wcvt_kernel<<<dim3(2048), blk, 0, stream>>>(ca, w16);
    }

    // ---- proj: obs -> bf16 pairwise into d_out, then z=2 GEMM into cat cols
    for (int p = 0; p < 2; ++p) {
        int n4 = (2 * NTOK * DMD) / 4;
        cvt_kernel<<<dim3((n4 + 255) / 256), blk, 0, stream>>>(
            obs + (size_t)p * 2 * NTOK * DMD, outu, n4);
        GArgs a{};
        for (int q = 0; q < 2; ++q) {
            int o = 2 * p + q;
            a.A[q]    = outu + (size_t)q * NTOK * DMD;
            a.W[q]    = projW16 + (size_t)o * DCC * DMD;
            a.bias[q] = proj_b + o * DCC;
            a.C[q]    = catbuf + o * DCC;        // ldc = 2048, column offset
        }
        gemm16<false, false><<<dim3(DCC/128, NTOK/128, 2), blk, 0, stream>>>(
            a, DMD, DMD, 0, 4 * DCC, DMD);
    }
    // ---- fuse: x0 = cat @ fuse_W^T + fuse_b  (K=2048)
    {
        GArgs a{};
        a.A[0] = catbuf; a.W[0] = fuseW16; a.bias[0] = fuse_b; a.C[0] = x0b;
        gemm16<false, false><<<dim3(DCC/128, NTOK/128, 1), blk, 0, stream>>>(
            a, 4 * DCC, 4 * DCC, 0, DCC, 4 * DCC);
    }

    // ---- initial bottom-up pass: fused GEMM+LN
    for (int i = 0; i < 4; ++i) {
        gemm_fused<0><<<dim3(NTOK/32), blk, 0, stream>>>(
            (i == 0) ? x0b : acts16[i - 1],
            upW16 + (size_t)i * DCC * DCC, up_b + i * DCC,
            ln_g + i * DCC, ln_b + i * DCC,
            nullptr, nullptr, nullptr, nullptr, acts16[i]);
    }

    // ---- settling iterations
    for (int s = 0; s < 5; ++s) {
        // batched independents: pred0, pred1, lat0..lat3 (all from pre-sweep acts)
        {
            GArgs a{};
            a.A[0] = acts16[1]; a.W[0] = downW16 + (size_t)1 * DCC * DCC;
            a.bias[0] = down_b + 1 * DCC; a.C[0] = pred16a;
            a.A[1] = acts16[2]; a.W[1] = downW16 + (size_t)2 * DCC * DCC;
            a.bias[1] = down_b + 2 * DCC; a.C[1] = pred16b;
            for (int i = 0; i < 4; ++i) {
                a.A[2 + i] = acts16[i];
                a.W[2 + i] = latW16 + (size_t)i * DCC * DCC;
                a.bias[2 + i] = lat_b + i * DCC;
                a.C[2 + i] = lat16[i];
            }
            gemm16<false, false><<<dim3(DCC/128, NTOK/128, 6), blk, 0, stream>>>(
                a, DCC, DCC, 0, DCC, DCC);
        }
        // sequential chain: fused up-GEMM + update per layer (in-place on acts)
        for (int i = 0; i < 4; ++i) {
            const unsigned short* tgt =
                (i == 0) ? pred16a : (i == 1) ? pred16b : acts16[i];
            gemm_fused<1><<<dim3(NTOK/32), blk, 0, stream>>>(
                (i == 0) ? x0b : acts16[i - 1],
                upW16 + (size_t)i * DCC * DCC, up_b + i * DCC,
                ln_g + i * DCC, ln_b + i * DCC,
                acts16[i], tgt, lat16[i], plogit + i * DCC, acts16[i]);
        }
    }

    // ---- head
    {
        GArgs a{};
        a.A[0] = acts16[3]; a.W[0] = out1W16; a.bias[0] = out1_b; a.C[0] = h16;
        gemm16<false, true><<<dim3(DCC/128, NTOK/128, 1), blk, 0, stream>>>(
            a, DCC, DCC, 0, DCC, DCC);
    }
    {
        GArgs a{};
        a.A[0] = h16; a.W[0] = out2W16; a.bias[0] = out2_b;
        a.add[0] = qwen; a.C[0] = out;
        gemm16<true, false><<<dim3(DMD/128, NTOK/128, 1), blk, 0, stream>>>(
            a, DCC, DCC, DMD, DMD, DCC);
    }
}